// Round 2
// baseline (189.058 us; speedup 1.0000x reference)
//
#include <hip/hip_runtime.h>
#include <stdint.h>
#include <math.h>

// Validated semantics (r17/r18 green): printed reference, fp32 in/out.
//   p[b,j] = mean_h sigmoid(delta/sqrt(32)),
//   delta[j,b,h] = sum_e D_e*(U+V),  D_e = (s_e-mu_s)-(o_e-mu_o)
//   Folded mu: sum_e D*w = sum_e (s-o)*w - ((sum s - sum o)/256)*sum_e w
//   U[h,e,j] = sum_{d in h} QwT[d,j]*Wk[d,e],  QwT = Qp[256+j]@Wq^T
//   V[b,h,e] = sum_{d in h} (Pq[b,d]+bq[d])*Wk[d,e],  Pq = pe[b]@Wq^T
//   new_state[b,e,l<256]=state; l>=256: p*s_l+(1-p)*o_{l-256}
//   atten[b,l,s]: l<256 -> 1 at s=l; else p at s=l, 1-p at s=l+256.
// This round: same as prior submission (infra failure, no signal) + explicit
// __launch_bounds__ on all kernels (pin regalloc to actual block shapes).
//   K1 coalesced via padded-LDS transpose tiles (was per-lane row gather
//   = 64 cache lines/wave-load); K3 float4 j-quads + 8-way e-split, 512 thr;
//   K4 float4 stores + float4 p reads.

// d_ws layout (floats) — unchanged
#define WS_P    0        // [32 b][256 j]  sum_h sigmoid
#define WS_QWT  8192     // [256 d][256 j]
#define WS_PQ   73728    // [32 b][256 d]
#define WS_U    81920    // [8 h][256 e][256 j]
#define WS_V    606208   // [32 b][8 h][256 e]

// ---------------------------------------------------------------------------
// K1 prologue: QwT (256 blocks), Pq (32), zero P (1). 289 blocks x 256.
// Both matvec families share one tiled path:
//   out[t] = sum_e lvec[e] * G[grow0 + t][e]
// G rows are staged through a padded [32][257] LDS tile so global loads are
// contiguous 128B segments (lanes = e) and LDS banks are (e+r)%32 (conflict-free).
__global__ void __launch_bounds__(256)
k_pro(const float* __restrict__ Qp, const float* __restrict__ Wq,
      float* __restrict__ ws) {
  int bid = blockIdx.x, t = threadIdx.x;
  if (bid < 288) {
    __shared__ float lvec[256];
    __shared__ float gt[32][257];
    const float* __restrict__ G;
    int grow0;
    float* dst;
    if (bid < 256) {                    // QwT[d][j] = sum_e Wq[d][e]*Qp[256+j][e]
      int d = bid;
      lvec[t] = Wq[(size_t)d * 256 + t];
      G = Qp; grow0 = 256; dst = ws + WS_QWT + d * 256;
    } else {                            // Pq[b][d] = sum_e pe[b][e]*Wq[d][e]
      int b = bid - 256;
      int k2 = t & ~1;                  // arange value 2k
      float div = expf((float)k2 * (-9.210340371976184f / 256.f));
      float a = (float)b * div;
      lvec[t] = (t & 1) ? cosf(a) : sinf(a);
      G = Wq; grow0 = 0; dst = ws + WS_PQ + b * 256;
    }
    __syncthreads();
    float acc = 0.f;
    int e = t & 31, rbase = t >> 5;
    for (int c = 0; c < 8; ++c) {       // 8 e-chunks of 32
      int e0 = c << 5;
      #pragma unroll 4
      for (int p8 = 0; p8 < 32; ++p8) { // stage G[grow0+r][e0+e] -> gt[e][r]
        int r = rbase + (p8 << 3);
        gt[e][r] = G[(size_t)(grow0 + r) * 256 + e0 + e];
      }
      __syncthreads();
      #pragma unroll
      for (int ee = 0; ee < 32; ++ee)
        acc += lvec[e0 + ee] * gt[ee][t];
      __syncthreads();
    }
    dst[t] = acc;
  } else {                              // zero P (ws re-poisoned every call)
    for (int i = t; i < 8192; i += 256) ws[WS_P + i] = 0.f;
  }
}

// ---------------------------------------------------------------------------
// K2: U[h][e][j] and V[b][h][e].  2304 blocks x 256.  (already coalesced)
__global__ void __launch_bounds__(256)
k_uv(const float* __restrict__ Wk, const float* __restrict__ bq,
     float* __restrict__ ws) {
  int bid = blockIdx.x, t = threadIdx.x;
  if (bid < 2048) {
    int h = bid >> 8, e = bid & 255;
    float acc = 0.f;
#pragma unroll 8
    for (int dd = 0; dd < 32; ++dd) {
      int d = h * 32 + dd;
      acc += ws[WS_QWT + d * 256 + t] * Wk[(size_t)d * 256 + e];
    }
    ws[WS_U + ((h << 8) + e) * 256 + t] = acc;
  } else {
    int idx = bid - 2048, b = idx >> 3, h = idx & 7;
    float acc = 0.f;
#pragma unroll 8
    for (int dd = 0; dd < 32; ++dd) {
      int d = h * 32 + dd;
      acc += (ws[WS_PQ + b * 256 + d] + bq[d]) * Wk[(size_t)d * 256 + t];
    }
    ws[WS_V + ((b << 3) + h) * 256 + t] = acc;
  }
}

// ---------------------------------------------------------------------------
// K3: delta with inline mu + sigmoid accumulate.
// 256 blocks = (b,h) x 512 threads. Thread = (e-eighth q, j-quad jg):
// float4 loads over j (contiguous axis), 32-deep e loop, padded-LDS reduction.
__global__ void __launch_bounds__(512)
k_delta(const float* __restrict__ state, const float* __restrict__ obs,
        float* __restrict__ ws) {
  int b = blockIdx.x >> 3, h = blockIdx.x & 7;
  int t = threadIdx.x;                  // 512 threads
  int q = t >> 6, jg = t & 63;          // e-eighth, j-quad (j = 4*jg..4*jg+3)
  __shared__ float vsh[256];
  __shared__ float red[512][17];        // +1 pad: bank = (17*t + k)%32 bijective
  if (t < 256) vsh[t] = ws[WS_V + ((b << 3) + h) * 256 + t];
  __syncthreads();
  const float* __restrict__ Uh = ws + WS_U + (h << 16);
  const float4* sp = (const float4*)(state + (size_t)b * 131072 + 256);
  const float4* op = (const float4*)(obs + (size_t)b * 65536);
  float4 a_sw = make_float4(0.f, 0.f, 0.f, 0.f);
  float4 a_w = a_sw, a_s = a_sw, a_o = a_sw;
  int e0 = q << 5;
  #pragma unroll 4
  for (int ei = 0; ei < 32; ++ei) {
    int e = e0 + ei;
    float4 s4 = sp[e * 128 + jg];                       // state[b,e,256+4jg..]
    float4 o4 = op[e * 64 + jg];                        // obs[b,e,4jg..]
    float4 u4 = ((const float4*)(Uh + (e << 8)))[jg];   // U[h,e,4jg..]
    float ve = vsh[e];
    float w0 = u4.x + ve, w1 = u4.y + ve, w2 = u4.z + ve, w3 = u4.w + ve;
    a_sw.x += (s4.x - o4.x) * w0;
    a_sw.y += (s4.y - o4.y) * w1;
    a_sw.z += (s4.z - o4.z) * w2;
    a_sw.w += (s4.w - o4.w) * w3;
    a_w.x += w0;   a_w.y += w1;   a_w.z += w2;   a_w.w += w3;
    a_s.x += s4.x; a_s.y += s4.y; a_s.z += s4.z; a_s.w += s4.w;
    a_o.x += o4.x; a_o.y += o4.y; a_o.z += o4.z; a_o.w += o4.w;
  }
  float* rr = red[t];
  rr[0]  = a_sw.x; rr[1]  = a_sw.y; rr[2]  = a_sw.z; rr[3]  = a_sw.w;
  rr[4]  = a_w.x;  rr[5]  = a_w.y;  rr[6]  = a_w.z;  rr[7]  = a_w.w;
  rr[8]  = a_s.x;  rr[9]  = a_s.y;  rr[10] = a_s.z;  rr[11] = a_s.w;
  rr[12] = a_o.x;  rr[13] = a_o.y;  rr[14] = a_o.z;  rr[15] = a_o.w;
  __syncthreads();
  if (t < 64) {
    float r[16];
    #pragma unroll
    for (int k = 0; k < 16; ++k) {
      float acc = red[t][k];
      #pragma unroll
      for (int qq = 1; qq < 8; ++qq) acc += red[(qq << 6) + t][k];
      r[k] = acc;
    }
    #pragma unroll
    for (int k = 0; k < 4; ++k) {
      // sum_e D*w = sum (s-o)w - mdiff*sum w,  mdiff = (sum s - sum o)/256
      float delta = r[k] - (r[8 + k] - r[12 + k]) * (1.f / 256.f) * r[4 + k];
      float ph = 1.f / (1.f + __expf(-delta * 0.17677669529663687f)); // /sqrt(32)
      atomicAdd(&ws[WS_P + b * 256 + (t << 2) + k], ph);
    }
  }
}

// ---------------------------------------------------------------------------
// K4 fused output. 16384 blocks: [0,4096) new_state (2 rows/block, float4);
// rest atten float4s (unchanged, write-bound).
__global__ void __launch_bounds__(256)
k_out(const float* __restrict__ state, const float* __restrict__ obs,
      const float* __restrict__ ws, float* __restrict__ out) {
  int bid = blockIdx.x, t = threadIdx.x;
  if (bid < 4096) {                     // new_state rows, float4/thread
    int row = (bid << 1) | (t >> 7);    // row = b*256 + e
    int tt = t & 127;                   // cols l = 4tt..4tt+3
    int b = row >> 8;
    float4 sv = ((const float4*)(state + (size_t)row * 512))[tt];
    float4* wrow = (float4*)(out + (size_t)row * 512);
    if (tt < 64) {
      wrow[tt] = sv;                    // l < 256: identity
    } else {
      float4 ov = ((const float4*)(obs + (size_t)row * 256))[tt - 64];
      float4 p4 = ((const float4*)(ws + WS_P + b * 256))[tt - 64];
      p4.x *= 0.125f; p4.y *= 0.125f; p4.z *= 0.125f; p4.w *= 0.125f;
      float4 r;
      r.x = p4.x * sv.x + (1.f - p4.x) * ov.x;
      r.y = p4.y * sv.y + (1.f - p4.y) * ov.y;
      r.z = p4.z * sv.z + (1.f - p4.z) * ov.z;
      r.w = p4.w * sv.w + (1.f - p4.w) * ov.w;
      wrow[tt] = r;
    }
  } else {                              // atten, one float4 per thread
    int g4 = (bid - 4096) * 256 + t;    // 0..3145727
    int r = g4 / 192, c = g4 - r * 192; // r = b*512 + l
    int b = r >> 9, l = r & 511;
    int s0 = c << 2;
    float v[4] = {0.f, 0.f, 0.f, 0.f};
    if (l < 256) {
      if (l >= s0 && l < s0 + 4) v[l - s0] = 1.0f;
    } else {
      float p = ws[WS_P + b * 256 + (l - 256)] * 0.125f;
      if (l >= s0 && l < s0 + 4) v[l - s0] = p;
      int s2 = l + 256;
      if (s2 >= s0 && s2 < s0 + 4) v[s2 - s0] = 1.0f - p;
    }
    float4 val; val.x = v[0]; val.y = v[1]; val.z = v[2]; val.w = v[3];
    ((float4*)(out + 4194304))[g4] = val;
  }
}

extern "C" void kernel_launch(void* const* d_in, const int* in_sizes, int n_in,
                              void* d_out, int out_size, void* d_ws, size_t ws_size,
                              hipStream_t stream) {
  const float *state = nullptr, *obs = nullptr, *Qp = nullptr;
  const float *Wq = nullptr, *Wk = nullptr, *bq = nullptr, *bk = nullptr;
  for (int i = 0; i < n_in; ++i) {
    int s = in_sizes[i];
    const float* p = (const float*)d_in[i];
    if      (s == 4194304) state = p;
    else if (s == 2097152) obs = p;
    else if (s == 131072)  Qp = p;
    else if (s == 65536)   { if (!Wq) Wq = p; else Wk = p; }
    else if (s == 256)     { if (!bq) bq = p; else bk = p; }
  }
  (void)bk;                             // cancels in the 2-way softmax
  float* out = (float*)d_out;
  float* ws  = (float*)d_ws;

  k_pro  <<<289,   256, 0, stream>>>(Qp, Wq, ws);
  k_uv   <<<2304,  256, 0, stream>>>(Wk, bq, ws);
  k_delta<<<256,   512, 0, stream>>>(state, obs, ws);
  k_out  <<<16384, 256, 0, stream>>>(state, obs, ws, out);
}

// Round 3
// 142.257 us; speedup vs baseline: 1.3290x; 1.3290x over previous
//
#include <hip/hip_runtime.h>
#include <stdint.h>
#include <math.h>

// Validated semantics (r17/r18 green): printed reference, fp32 in/out.
//   p[b,j] = mean_h sigmoid(delta/sqrt(32)),
//   delta[j,b,h] = sum_e D_e*(U+V),  D_e = (s_e-mu_s)-(o_e-mu_o)
//   Folded mu: sum_e D*w = sum_e (s-o)*w - ((sum s - sum o)/256)*sum_e w
//   U[h,e,j] = sum_{d in h} QwT[d,j]*Wk[d,e],  QwT = Qp[256+j]@Wq^T
//   V[b,h,e] = sum_{d in h} (Pq[b,d]+bq[d])*Wk[d,e],  Pq = pe[b]@Wq^T
//   new_state[b,e,l<256]=state; l>=256: p*s_l+(1-p)*o_{l-256}
//   atten[b,l,s]: l<256 -> 1 at s=l; else p at s=l, 1-p at s=l+256.
// This round: r1's chunked-LDS K1 was latency-serialized (62us, occ 6%,
// VGPR 236). Replace with k_tr pre-transpose (QpT, WqT in ws) + k_pro as
// pure coalesced L2 streams, no inner syncs. K2/K3/K4 unchanged (passing).

// d_ws layout (floats)
#define WS_P    0        // [32 b][256 j]  sum_h sigmoid
#define WS_QWT  8192     // [256 d][256 j]
#define WS_PQ   73728    // [32 b][256 d]
#define WS_U    81920    // [8 h][256 e][256 j]
#define WS_V    606208   // [32 b][8 h][256 e]
#define WS_QPT  671744   // [256 e][256 j]  QpT[e][j] = Qp[256+j][e]
#define WS_WQT  737280   // [256 e][256 d]  WqT[e][d] = Wq[d][e]
// end 802816 floats = 3.06 MB (ws_size >= 3.3 MB proven in r2-r4)

// ---------------------------------------------------------------------------
// K0 transpose: QpT and WqT via padded 32x32 LDS tiles. 128 blocks x 256.
__global__ void __launch_bounds__(256)
k_tr(const float* __restrict__ Qp, const float* __restrict__ Wq,
     float* __restrict__ ws) {
  __shared__ float tile[32][33];
  int bid = blockIdx.x, t = threadIdx.x;
  const float* src; float* dst; int ti;
  if (bid < 64) { src = Qp + 65536; dst = ws + WS_QPT; ti = bid; }
  else          { src = Wq;         dst = ws + WS_WQT; ti = bid - 64; }
  int tr = ti >> 3, tc = ti & 7;        // row-tile (j/d), col-tile (e)
  int c = t & 31, r0 = t >> 5;
  #pragma unroll
  for (int k = 0; k < 4; ++k) {         // load src tile, coalesced
    int r = r0 + (k << 3);
    tile[r][c] = src[(size_t)(tr * 32 + r) * 256 + tc * 32 + c];
  }
  __syncthreads();
  #pragma unroll
  for (int k = 0; k < 4; ++k) {         // store transposed, coalesced
    int r = r0 + (k << 3);
    dst[(size_t)(tc * 32 + r) * 256 + tr * 32 + c] = tile[c][r];
  }
}

// ---------------------------------------------------------------------------
// K1 prologue: QwT (256 blocks), Pq (32), zero P (1). 289 blocks x 256.
// out[t] = sum_e lvec[e] * GT[e][t] — lvec broadcast from LDS, GT a dense
// lane-coalesced L2 stream. No syncs inside the loop.
__global__ void __launch_bounds__(256)
k_pro(const float* __restrict__ Wq, float* __restrict__ ws) {
  int bid = blockIdx.x, t = threadIdx.x;
  if (bid < 288) {
    __shared__ float lvec[256];
    const float* __restrict__ GT; float* dst;
    if (bid < 256) {                    // QwT[d][j] = sum_e Wq[d][e]*QpT[e][j]
      int d = bid;
      lvec[t] = Wq[(size_t)d * 256 + t];
      GT = ws + WS_QPT; dst = ws + WS_QWT + d * 256;
    } else {                            // Pq[b][d] = sum_e pe[b][e]*WqT[e][d]
      int b = bid - 256;
      int k2 = t & ~1;                  // arange value 2k
      float div = expf((float)k2 * (-9.210340371976184f / 256.f));
      float a = (float)b * div;
      lvec[t] = (t & 1) ? cosf(a) : sinf(a);
      GT = ws + WS_WQT; dst = ws + WS_PQ + b * 256;
    }
    __syncthreads();
    float acc = 0.f;
    #pragma unroll 8
    for (int e = 0; e < 256; ++e)
      acc += lvec[e] * GT[(e << 8) + t];
    dst[t] = acc;
  } else {                              // zero P (ws re-poisoned every call)
    for (int i = t; i < 8192; i += 256) ws[WS_P + i] = 0.f;
  }
}

// ---------------------------------------------------------------------------
// K2: U[h][e][j] and V[b][h][e].  2304 blocks x 256.  (already coalesced)
__global__ void __launch_bounds__(256)
k_uv(const float* __restrict__ Wk, const float* __restrict__ bq,
     float* __restrict__ ws) {
  int bid = blockIdx.x, t = threadIdx.x;
  if (bid < 2048) {
    int h = bid >> 8, e = bid & 255;
    float acc = 0.f;
#pragma unroll 8
    for (int dd = 0; dd < 32; ++dd) {
      int d = h * 32 + dd;
      acc += ws[WS_QWT + d * 256 + t] * Wk[(size_t)d * 256 + e];
    }
    ws[WS_U + ((h << 8) + e) * 256 + t] = acc;
  } else {
    int idx = bid - 2048, b = idx >> 3, h = idx & 7;
    float acc = 0.f;
#pragma unroll 8
    for (int dd = 0; dd < 32; ++dd) {
      int d = h * 32 + dd;
      acc += (ws[WS_PQ + b * 256 + d] + bq[d]) * Wk[(size_t)d * 256 + t];
    }
    ws[WS_V + ((b << 3) + h) * 256 + t] = acc;
  }
}

// ---------------------------------------------------------------------------
// K3: delta with inline mu + sigmoid accumulate.
// 256 blocks = (b,h) x 512 threads. Thread = (e-eighth q, j-quad jg):
// float4 loads over j (contiguous axis), 32-deep e loop, padded-LDS reduction.
__global__ void __launch_bounds__(512)
k_delta(const float* __restrict__ state, const float* __restrict__ obs,
        float* __restrict__ ws) {
  int b = blockIdx.x >> 3, h = blockIdx.x & 7;
  int t = threadIdx.x;                  // 512 threads
  int q = t >> 6, jg = t & 63;          // e-eighth, j-quad (j = 4*jg..4*jg+3)
  __shared__ float vsh[256];
  __shared__ float red[512][17];        // +1 pad: bank = (17*t + k)%32 bijective
  if (t < 256) vsh[t] = ws[WS_V + ((b << 3) + h) * 256 + t];
  __syncthreads();
  const float* __restrict__ Uh = ws + WS_U + (h << 16);
  const float4* sp = (const float4*)(state + (size_t)b * 131072 + 256);
  const float4* op = (const float4*)(obs + (size_t)b * 65536);
  float4 a_sw = make_float4(0.f, 0.f, 0.f, 0.f);
  float4 a_w = a_sw, a_s = a_sw, a_o = a_sw;
  int e0 = q << 5;
  #pragma unroll 4
  for (int ei = 0; ei < 32; ++ei) {
    int e = e0 + ei;
    float4 s4 = sp[e * 128 + jg];                       // state[b,e,256+4jg..]
    float4 o4 = op[e * 64 + jg];                        // obs[b,e,4jg..]
    float4 u4 = ((const float4*)(Uh + (e << 8)))[jg];   // U[h,e,4jg..]
    float ve = vsh[e];
    float w0 = u4.x + ve, w1 = u4.y + ve, w2 = u4.z + ve, w3 = u4.w + ve;
    a_sw.x += (s4.x - o4.x) * w0;
    a_sw.y += (s4.y - o4.y) * w1;
    a_sw.z += (s4.z - o4.z) * w2;
    a_sw.w += (s4.w - o4.w) * w3;
    a_w.x += w0;   a_w.y += w1;   a_w.z += w2;   a_w.w += w3;
    a_s.x += s4.x; a_s.y += s4.y; a_s.z += s4.z; a_s.w += s4.w;
    a_o.x += o4.x; a_o.y += o4.y; a_o.z += o4.z; a_o.w += o4.w;
  }
  float* rr = red[t];
  rr[0]  = a_sw.x; rr[1]  = a_sw.y; rr[2]  = a_sw.z; rr[3]  = a_sw.w;
  rr[4]  = a_w.x;  rr[5]  = a_w.y;  rr[6]  = a_w.z;  rr[7]  = a_w.w;
  rr[8]  = a_s.x;  rr[9]  = a_s.y;  rr[10] = a_s.z;  rr[11] = a_s.w;
  rr[12] = a_o.x;  rr[13] = a_o.y;  rr[14] = a_o.z;  rr[15] = a_o.w;
  __syncthreads();
  if (t < 64) {
    float r[16];
    #pragma unroll
    for (int k = 0; k < 16; ++k) {
      float acc = red[t][k];
      #pragma unroll
      for (int qq = 1; qq < 8; ++qq) acc += red[(qq << 6) + t][k];
      r[k] = acc;
    }
    #pragma unroll
    for (int k = 0; k < 4; ++k) {
      // sum_e D*w = sum (s-o)w - mdiff*sum w,  mdiff = (sum s - sum o)/256
      float delta = r[k] - (r[8 + k] - r[12 + k]) * (1.f / 256.f) * r[4 + k];
      float ph = 1.f / (1.f + __expf(-delta * 0.17677669529663687f)); // /sqrt(32)
      atomicAdd(&ws[WS_P + b * 256 + (t << 2) + k], ph);
    }
  }
}

// ---------------------------------------------------------------------------
// K4 fused output. 16384 blocks: [0,4096) new_state (2 rows/block, float4);
// rest atten float4s (write-bound).
__global__ void __launch_bounds__(256)
k_out(const float* __restrict__ state, const float* __restrict__ obs,
      const float* __restrict__ ws, float* __restrict__ out) {
  int bid = blockIdx.x, t = threadIdx.x;
  if (bid < 4096) {                     // new_state rows, float4/thread
    int row = (bid << 1) | (t >> 7);    // row = b*256 + e
    int tt = t & 127;                   // cols l = 4tt..4tt+3
    int b = row >> 8;
    float4 sv = ((const float4*)(state + (size_t)row * 512))[tt];
    float4* wrow = (float4*)(out + (size_t)row * 512);
    if (tt < 64) {
      wrow[tt] = sv;                    // l < 256: identity
    } else {
      float4 ov = ((const float4*)(obs + (size_t)row * 256))[tt - 64];
      float4 p4 = ((const float4*)(ws + WS_P + b * 256))[tt - 64];
      p4.x *= 0.125f; p4.y *= 0.125f; p4.z *= 0.125f; p4.w *= 0.125f;
      float4 r;
      r.x = p4.x * sv.x + (1.f - p4.x) * ov.x;
      r.y = p4.y * sv.y + (1.f - p4.y) * ov.y;
      r.z = p4.z * sv.z + (1.f - p4.z) * ov.z;
      r.w = p4.w * sv.w + (1.f - p4.w) * ov.w;
      wrow[tt] = r;
    }
  } else {                              // atten, one float4 per thread
    int g4 = (bid - 4096) * 256 + t;    // 0..3145727
    int r = g4 / 192, c = g4 - r * 192; // r = b*512 + l
    int b = r >> 9, l = r & 511;
    int s0 = c << 2;
    float v[4] = {0.f, 0.f, 0.f, 0.f};
    if (l < 256) {
      if (l >= s0 && l < s0 + 4) v[l - s0] = 1.0f;
    } else {
      float p = ws[WS_P + b * 256 + (l - 256)] * 0.125f;
      if (l >= s0 && l < s0 + 4) v[l - s0] = p;
      int s2 = l + 256;
      if (s2 >= s0 && s2 < s0 + 4) v[s2 - s0] = 1.0f - p;
    }
    float4 val; val.x = v[0]; val.y = v[1]; val.z = v[2]; val.w = v[3];
    ((float4*)(out + 4194304))[g4] = val;
  }
}

extern "C" void kernel_launch(void* const* d_in, const int* in_sizes, int n_in,
                              void* d_out, int out_size, void* d_ws, size_t ws_size,
                              hipStream_t stream) {
  const float *state = nullptr, *obs = nullptr, *Qp = nullptr;
  const float *Wq = nullptr, *Wk = nullptr, *bq = nullptr, *bk = nullptr;
  for (int i = 0; i < n_in; ++i) {
    int s = in_sizes[i];
    const float* p = (const float*)d_in[i];
    if      (s == 4194304) state = p;
    else if (s == 2097152) obs = p;
    else if (s == 131072)  Qp = p;
    else if (s == 65536)   { if (!Wq) Wq = p; else Wk = p; }
    else if (s == 256)     { if (!bq) bq = p; else bk = p; }
  }
  (void)bk;                             // cancels in the 2-way softmax
  float* out = (float*)d_out;
  float* ws  = (float*)d_ws;

  k_tr   <<<128,   256, 0, stream>>>(Qp, Wq, ws);
  k_pro  <<<289,   256, 0, stream>>>(Wq, ws);
  k_uv   <<<2304,  256, 0, stream>>>(Wk, bq, ws);
  k_delta<<<256,   512, 0, stream>>>(state, obs, ws);
  k_out  <<<16384, 256, 0, stream>>>(state, obs, ws, out);
}

// Round 4
// 131.175 us; speedup vs baseline: 1.4413x; 1.0845x over previous
//
#include <hip/hip_runtime.h>
#include <stdint.h>
#include <math.h>

// Validated semantics (r17/r18 green): printed reference, fp32 in/out.
//   p[b,j] = mean_h sigmoid(delta/sqrt(32)),
//   delta[j,b,h] = sum_e D_e*(U+V),  D_e = (s_e-mu_s)-(o_e-mu_o)
//   Folded mu: sum_e D*w = sum_e (s-o)*w - ((sum s - sum o)/256)*sum_e w
//   U[h,e,j] = sum_{d in h} QwT[d,j]*Wk[d,e],  QwT = Qp[256+j]@Wq^T
//   V[b,h,e] = sum_{d in h} (Pq[b,d]+bq[d])*Wk[d,e],  Pq = pe[b]@Wq^T
//   new_state[b,e,l<256]=state; l>=256: p*s_l+(1-p)*o_{l-256}
//   atten[b,l,s]: l<256 -> 1 at s=l; else p at s=l, 1-p at s=l+256.
// This round: k_delta restructured as (b, j-tile32) x all-8-h blocks with
// X=s-o staged in LDS once (global traffic 192->84 MB, state/obs read 1x not
// 8x), in-LDS h-reduction -> no atomics, no zero-P pass (k_pro now 288).
// k_tr/k_pro/k_uv/k_out unchanged from the 142us build.

// d_ws layout (floats)
#define WS_P    0        // [32 b][256 j]  sum_h sigmoid
#define WS_QWT  8192     // [256 d][256 j]
#define WS_PQ   73728    // [32 b][256 d]
#define WS_U    81920    // [8 h][256 e][256 j]
#define WS_V    606208   // [32 b][8 h][256 e]
#define WS_QPT  671744   // [256 e][256 j]  QpT[e][j] = Qp[256+j][e]
#define WS_WQT  737280   // [256 e][256 d]  WqT[e][d] = Wq[d][e]
// end 802816 floats = 3.06 MB (ws_size >= 3.3 MB proven in r2-r4)

// ---------------------------------------------------------------------------
// K0 transpose: QpT and WqT via padded 32x32 LDS tiles. 128 blocks x 256.
__global__ void __launch_bounds__(256)
k_tr(const float* __restrict__ Qp, const float* __restrict__ Wq,
     float* __restrict__ ws) {
  __shared__ float tile[32][33];
  int bid = blockIdx.x, t = threadIdx.x;
  const float* src; float* dst; int ti;
  if (bid < 64) { src = Qp + 65536; dst = ws + WS_QPT; ti = bid; }
  else          { src = Wq;         dst = ws + WS_WQT; ti = bid - 64; }
  int tr = ti >> 3, tc = ti & 7;        // row-tile (j/d), col-tile (e)
  int c = t & 31, r0 = t >> 5;
  #pragma unroll
  for (int k = 0; k < 4; ++k) {         // load src tile, coalesced
    int r = r0 + (k << 3);
    tile[r][c] = src[(size_t)(tr * 32 + r) * 256 + tc * 32 + c];
  }
  __syncthreads();
  #pragma unroll
  for (int k = 0; k < 4; ++k) {         // store transposed, coalesced
    int r = r0 + (k << 3);
    dst[(size_t)(tc * 32 + r) * 256 + tr * 32 + c] = tile[c][r];
  }
}

// ---------------------------------------------------------------------------
// K1 prologue: QwT (256 blocks), Pq (32). 288 blocks x 256.
// out[t] = sum_e lvec[e] * GT[e][t] — lvec broadcast from LDS, GT a dense
// lane-coalesced L2 stream. No syncs inside the loop. (zero-P dropped: the
// new k_delta writes P directly.)
__global__ void __launch_bounds__(256)
k_pro(const float* __restrict__ Wq, float* __restrict__ ws) {
  int bid = blockIdx.x, t = threadIdx.x;
  __shared__ float lvec[256];
  const float* __restrict__ GT; float* dst;
  if (bid < 256) {                      // QwT[d][j] = sum_e Wq[d][e]*QpT[e][j]
    int d = bid;
    lvec[t] = Wq[(size_t)d * 256 + t];
    GT = ws + WS_QPT; dst = ws + WS_QWT + d * 256;
  } else {                              // Pq[b][d] = sum_e pe[b][e]*WqT[e][d]
    int b = bid - 256;
    int k2 = t & ~1;                    // arange value 2k
    float div = expf((float)k2 * (-9.210340371976184f / 256.f));
    float a = (float)b * div;
    lvec[t] = (t & 1) ? cosf(a) : sinf(a);
    GT = ws + WS_WQT; dst = ws + WS_PQ + b * 256;
  }
  __syncthreads();
  float acc = 0.f;
  #pragma unroll 8
  for (int e = 0; e < 256; ++e)
    acc += lvec[e] * GT[(e << 8) + t];
  dst[t] = acc;
}

// ---------------------------------------------------------------------------
// K2: U[h][e][j] and V[b][h][e].  2304 blocks x 256.  (already coalesced)
__global__ void __launch_bounds__(256)
k_uv(const float* __restrict__ Wk, const float* __restrict__ bq,
     float* __restrict__ ws) {
  int bid = blockIdx.x, t = threadIdx.x;
  if (bid < 2048) {
    int h = bid >> 8, e = bid & 255;
    float acc = 0.f;
#pragma unroll 8
    for (int dd = 0; dd < 32; ++dd) {
      int d = h * 32 + dd;
      acc += ws[WS_QWT + d * 256 + t] * Wk[(size_t)d * 256 + e];
    }
    ws[WS_U + ((h << 8) + e) * 256 + t] = acc;
  } else {
    int idx = bid - 2048, b = idx >> 3, h = idx & 7;
    float acc = 0.f;
#pragma unroll 8
    for (int dd = 0; dd < 32; ++dd) {
      int d = h * 32 + dd;
      acc += (ws[WS_PQ + b * 256 + d] + bq[d]) * Wk[(size_t)d * 256 + t];
    }
    ws[WS_V + ((b << 3) + h) * 256 + t] = acc;
  }
}

// ---------------------------------------------------------------------------
// K3: delta, restructured. 256 blocks = (b, j-tile of 32) x 256 threads.
// Stage X[e][j]=s-o (LDS, padded 33) + V[b][:][:] slice once; loop all 8 h
// in-block; reduce partials in LDS; write P[b, jt..jt+31] directly (no
// atomics, no zero-P). delta = sum_e X*w - (sum_e X)/256 * sum_e w, w=U+V.
__global__ void __launch_bounds__(256)
k_delta(const float* __restrict__ state, const float* __restrict__ obs,
        float* __restrict__ ws) {
  int b = blockIdx.x >> 3, jt = (blockIdx.x & 7) << 5;
  int t = threadIdx.x;
  __shared__ float Xs[256][33];         // X[e][j], +1 pad -> <=2-way (free)
  __shared__ float Vs[2048];            // V[b][h][e] slice
  __shared__ float pd[8][8][32];        // [eg][h][j] partial sum X*w
  __shared__ float pw[8][8][32];        // [eg][h][j] partial sum w
  __shared__ float px[8][32];           // [eg][j]    partial sum X (reused)
  {                                     // stage: (es 0..31, jq 0..7) float4
    int es = t >> 3, jq = t & 7;
    const float* sp = state + (size_t)b * 131072 + 256 + jt + (jq << 2);
    const float* op = obs   + (size_t)b * 65536  + jt + (jq << 2);
    #pragma unroll
    for (int k = 0; k < 8; ++k) {
      int e = es + (k << 5);
      float4 s4 = *(const float4*)(sp + (size_t)e * 512);
      float4 o4 = *(const float4*)(op + (size_t)e * 256);
      float* xr = &Xs[e][jq << 2];
      xr[0] = s4.x - o4.x; xr[1] = s4.y - o4.y;
      xr[2] = s4.z - o4.z; xr[3] = s4.w - o4.w;
    }
    for (int i = t; i < 2048; i += 256) Vs[i] = ws[WS_V + (b << 11) + i];
  }
  __syncthreads();
  int j = t & 31, eg = t >> 5, e0 = eg << 5;
  {                                     // a_x partial (h-independent)
    float ax = 0.f;
    #pragma unroll
    for (int ei = 0; ei < 32; ++ei) ax += Xs[e0 + ei][j];
    px[eg][j] = ax;
  }
  const float* __restrict__ Ub = ws + WS_U + jt + j;
  #pragma unroll
  for (int h = 0; h < 8; ++h) {
    float dacc = 0.f, wacc = 0.f;
    const float* __restrict__ Uh = Ub + (h << 16) + (e0 << 8);
    const float* __restrict__ Vh = Vs + (h << 8) + e0;
    #pragma unroll 16
    for (int ei = 0; ei < 32; ++ei) {
      float w = Uh[ei << 8] + Vh[ei];
      dacc += Xs[e0 + ei][j] * w;
      wacc += w;
    }
    pd[eg][h][j] = dacc;
    pw[eg][h][j] = wacc;
  }
  __syncthreads();
  int h2 = t >> 5, j2 = t & 31;         // thread -> (h, j) for the merge
  float D = 0.f, W = 0.f, X = 0.f;
  #pragma unroll
  for (int g = 0; g < 8; ++g) {
    D += pd[g][h2][j2];
    W += pw[g][h2][j2];
    X += px[g][j2];
  }
  float delta = D - X * (1.f / 256.f) * W;
  float sig = 1.f / (1.f + __expf(-delta * 0.17677669529663687f)); // /sqrt(32)
  __syncthreads();
  px[h2][j2] = sig;                     // reuse px as [h][j] sigmoid buffer
  __syncthreads();
  if (t < 32) {
    float acc = 0.f;
    #pragma unroll
    for (int h = 0; h < 8; ++h) acc += px[h][t];
    ws[WS_P + (b << 8) + jt + t] = acc; // sum_h; k_out applies *0.125
  }
}

// ---------------------------------------------------------------------------
// K4 fused output. 16384 blocks: [0,4096) new_state (2 rows/block, float4);
// rest atten float4s (write-bound).
__global__ void __launch_bounds__(256)
k_out(const float* __restrict__ state, const float* __restrict__ obs,
      const float* __restrict__ ws, float* __restrict__ out) {
  int bid = blockIdx.x, t = threadIdx.x;
  if (bid < 4096) {                     // new_state rows, float4/thread
    int row = (bid << 1) | (t >> 7);    // row = b*256 + e
    int tt = t & 127;                   // cols l = 4tt..4tt+3
    int b = row >> 8;
    float4 sv = ((const float4*)(state + (size_t)row * 512))[tt];
    float4* wrow = (float4*)(out + (size_t)row * 512);
    if (tt < 64) {
      wrow[tt] = sv;                    // l < 256: identity
    } else {
      float4 ov = ((const float4*)(obs + (size_t)row * 256))[tt - 64];
      float4 p4 = ((const float4*)(ws + WS_P + b * 256))[tt - 64];
      p4.x *= 0.125f; p4.y *= 0.125f; p4.z *= 0.125f; p4.w *= 0.125f;
      float4 r;
      r.x = p4.x * sv.x + (1.f - p4.x) * ov.x;
      r.y = p4.y * sv.y + (1.f - p4.y) * ov.y;
      r.z = p4.z * sv.z + (1.f - p4.z) * ov.z;
      r.w = p4.w * sv.w + (1.f - p4.w) * ov.w;
      wrow[tt] = r;
    }
  } else {                              // atten, one float4 per thread
    int g4 = (bid - 4096) * 256 + t;    // 0..3145727
    int r = g4 / 192, c = g4 - r * 192; // r = b*512 + l
    int b = r >> 9, l = r & 511;
    int s0 = c << 2;
    float v[4] = {0.f, 0.f, 0.f, 0.f};
    if (l < 256) {
      if (l >= s0 && l < s0 + 4) v[l - s0] = 1.0f;
    } else {
      float p = ws[WS_P + b * 256 + (l - 256)] * 0.125f;
      if (l >= s0 && l < s0 + 4) v[l - s0] = p;
      int s2 = l + 256;
      if (s2 >= s0 && s2 < s0 + 4) v[s2 - s0] = 1.0f - p;
    }
    float4 val; val.x = v[0]; val.y = v[1]; val.z = v[2]; val.w = v[3];
    ((float4*)(out + 4194304))[g4] = val;
  }
}

extern "C" void kernel_launch(void* const* d_in, const int* in_sizes, int n_in,
                              void* d_out, int out_size, void* d_ws, size_t ws_size,
                              hipStream_t stream) {
  const float *state = nullptr, *obs = nullptr, *Qp = nullptr;
  const float *Wq = nullptr, *Wk = nullptr, *bq = nullptr, *bk = nullptr;
  for (int i = 0; i < n_in; ++i) {
    int s = in_sizes[i];
    const float* p = (const float*)d_in[i];
    if      (s == 4194304) state = p;
    else if (s == 2097152) obs = p;
    else if (s == 131072)  Qp = p;
    else if (s == 65536)   { if (!Wq) Wq = p; else Wk = p; }
    else if (s == 256)     { if (!bq) bq = p; else bk = p; }
  }
  (void)bk;                             // cancels in the 2-way softmax
  float* out = (float*)d_out;
  float* ws  = (float*)d_ws;

  k_tr   <<<128,   256, 0, stream>>>(Qp, Wq, ws);
  k_pro  <<<288,   256, 0, stream>>>(Wq, ws);
  k_uv   <<<2304,  256, 0, stream>>>(Wk, bq, ws);
  k_delta<<<256,   256, 0, stream>>>(state, obs, ws);
  k_out  <<<16384, 256, 0, stream>>>(state, obs, ws, out);
}